// Round 5
// baseline (206.307 us; speedup 1.0000x reference)
//
#include <hip/hip_runtime.h>
#include <math.h>

// Problem constants
#define KCODES 1024
#define DDIM   64

// Output layout (floats), concatenated in reference return order:
// z_q_out [16,64,64,64], idx_out [16,64,64], emb_new [64,1024],
// emb_ema_new [64,1024], counts_ema_new [1024]
constexpr size_t O_ZQ  = 0;
constexpr size_t O_IDX = 4194304;
constexpr size_t O_EMB = O_IDX + 65536;   // 4259840
constexpr size_t O_EMA = O_EMB + 65536;   // 4325376
constexpr size_t O_CEN = O_EMA + 65536;   // 4390912

// Workspace layout (float offsets)
constexpr size_t W_UPD   = 0;              // [K][D] segment-sum accumulator
constexpr size_t W_CNT   = 65536;          // [K] histogram
constexpr size_t W_ENORM = W_CNT + 1024;   // [K] ||e_k||^2
constexpr size_t W_EMBT  = W_ENORM + 1024; // [K][D] transposed codebook

// async global->LDS, 16B per lane; LDS dest is wave-uniform base,
// lane data lands at base + lane*16.
__device__ __forceinline__ void gload16(const float* g, float* l) {
  __builtin_amdgcn_global_load_lds(
      (const __attribute__((address_space(1))) void*)g,
      (__attribute__((address_space(3))) void*)l, 16, 0, 0);
}

// ---------------------------------------------------------------------------
// K1: LDS-tiled transpose emb[D][K] -> embT[K][D], eNorm, zero W_UPD/W_CNT.
// 16 blocks; block g handles codes k0 = g*64 .. k0+63.
__global__ __launch_bounds__(256) void vq_prep(const float* __restrict__ emb,
                                               float* __restrict__ ws) {
  __shared__ float t_lds[64 * 65];          // [d][k] padded (+1)
  const int tid = threadIdx.x;
  const int g   = blockIdx.x;
  const int k0  = g * 64;

  // coalesced load: 64 contiguous floats per wave-instruction
  #pragma unroll
  for (int it = 0; it < 16; ++it) {
    const int idx = tid + it * 256;         // 0..4095
    const int d   = idx >> 6;
    const int kq  = idx & 63;
    t_lds[d * 65 + kq] = emb[d * KCODES + k0 + kq];
  }
  __syncthreads();

  // coalesced store: lanes vary d (contiguous in embT); LDS read stride 65
  // -> banks l%32, 2-way aliasing = free
  #pragma unroll
  for (int it = 0; it < 16; ++it) {
    const int idx = tid + it * 256;
    const int k   = idx >> 6;
    const int d   = idx & 63;
    ws[W_EMBT + (size_t)(k0 + k) * 64 + d] = t_lds[d * 65 + k];
  }

  // eNorm for this block's 64 codes (d-sequential sum, matches prior rounds)
  if (tid < 64) {
    const int k = tid;
    float s = 0.f;
    #pragma unroll
    for (int d = 0; d < DDIM; ++d) {
      const float v = t_lds[d * 65 + k];
      s = fmaf(v, v, s);
    }
    ws[W_ENORM + k0 + k] = s;
  }

  // zero accumulators: W_UPD block slice (4096 floats) + W_CNT slice (64)
  float4* u4 = (float4*)(ws + W_UPD);
  #pragma unroll
  for (int j = 0; j < 4; ++j) u4[g * 1024 + tid + j * 256] = float4{0.f, 0.f, 0.f, 0.f};
  if (tid < 64) ws[W_CNT + k0 + tid] = 0.f;
}

// ---------------------------------------------------------------------------
// K2: distance GEMM + argmin + fused epilogue.
// Block: 256 threads = 16 rowgrps x 16 colgrps; 128 rows/block; per-thread
// 8 rows x 16 codes (codes strided colgrp*4 + q*64 + j -> bank-safe).
// z tile staged async once; e tiles [16][256] double-buffered via
// global_load_lds: issue phase g+1 right after barrier g, compute phase g.
// LDS: z 32 KB + 2 x 8 KB e = 48 KB -> 2 blocks/CU (VGPR-capped).
__global__ __launch_bounds__(256, 2) void vq_main(const float* __restrict__ z_e,
                                                  const float* __restrict__ emb,
                                                  float* ws,
                                                  float* __restrict__ out) {
  __shared__ float z_lds[DDIM * 128];   // [d][row] 32 KB
  __shared__ float e_lds0[16 * 256];    // [dp][code] 8 KB (buf 0; bidx overlay)
  __shared__ float e_lds1[16 * 256];    // [dp][code] 8 KB (buf 1)

  const int tid  = threadIdx.x;
  const int bid  = blockIdx.x;
  const int wv   = tid >> 6;
  const int lane = tid & 63;

  const int rowgrp = tid >> 4;          // 0..15
  const int colgrp = tid & 15;          // 0..15
  const int r0     = rowgrp * 8;
  const int c0t    = colgrp * 4;

  const int n0  = bid * 128;
  const int b   = n0 >> 12;
  const int hw0 = n0 & 4095;

  // --- async stage z tile [64][128]: 8 x 1KB instructions per wave ---
  {
    const float* zsrc = z_e + (size_t)b * 262144 + hw0;
    #pragma unroll
    for (int it = 0; it < 8; ++it) {
      const int d0 = wv * 16 + it * 2;  // this inst covers rows d0, d0+1
      const float* g =
          zsrc + (size_t)(d0 + (lane >> 5)) * 4096 + (size_t)(lane & 31) * 4;
      gload16(g, &z_lds[d0 * 128]);
    }
  }

  // --- e-stage issue: tile [16][256] <- emb[dstart+dp][c0..c0+255] ---
  auto issue_e = [&](float* ebuf, int chunk, int dstart) {
    const float* esrc =
        emb + (size_t)dstart * KCODES + (size_t)chunk * 256 + (size_t)lane * 4;
    #pragma unroll
    for (int it = 0; it < 4; ++it) {
      const int dp = wv * 4 + it;
      gload16(esrc + (size_t)dp * KCODES, &ebuf[dp * 256]);
    }
  };

  issue_e(e_lds0, 0, 0);   // prologue: phase g=0

  const float* __restrict__ eN = ws + W_ENORM;

  float minval[8];
  int   minidx[8];
  #pragma unroll
  for (int i = 0; i < 8; ++i) { minval[i] = INFINITY; minidx[i] = 0; }

  for (int chunk = 0; chunk < 4; ++chunk) {
    const int c0 = chunk * 256;

    float acc[8][16];
    #pragma unroll
    for (int i = 0; i < 8; ++i)
      #pragma unroll
      for (int j = 0; j < 16; ++j) acc[i][j] = 0.f;

    #pragma unroll
    for (int p = 0; p < 4; ++p) {
      // This wave's outstanding DMAs here are exactly phase g's (issued one
      // full phase ago); compiler's vmcnt(0)-before-barrier is the needed wait.
      __syncthreads();

      const int g = chunk * 4 + p;
      if (g < 15) {                 // prefetch g+1 into the other buffer
        const int gn = g + 1;
        issue_e((gn & 1) ? e_lds1 : e_lds0, gn >> 2, (gn & 3) * 16);
      }

      const float* ebuf = (p & 1) ? e_lds1 : e_lds0;
      const int dbase = p * 16;

      #pragma unroll 4
      for (int dp = 0; dp < 16; ++dp) {
        const int d = dbase + dp;
        float zf[8], ef[16];
        const float4 za = *(const float4*)(z_lds + d * 128 + r0);
        const float4 zb = *(const float4*)(z_lds + d * 128 + r0 + 4);
        zf[0]=za.x; zf[1]=za.y; zf[2]=za.z; zf[3]=za.w;
        zf[4]=zb.x; zf[5]=zb.y; zf[6]=zb.z; zf[7]=zb.w;
        #pragma unroll
        for (int q = 0; q < 4; ++q) {
          const float4 ev = *(const float4*)(ebuf + dp * 256 + c0t + q * 64);
          ef[4*q+0]=ev.x; ef[4*q+1]=ev.y; ef[4*q+2]=ev.z; ef[4*q+3]=ev.w;
        }
        #pragma unroll
        for (int i = 0; i < 8; ++i)
          #pragma unroll
          for (int j = 0; j < 16; ++j)
            acc[i][j] = fmaf(zf[i], ef[j], acc[i][j]);
      }
    }

    // ---- fold this chunk into the running argmin ----
    float en[16];
    #pragma unroll
    for (int q = 0; q < 4; ++q) {
      const float4 v = *(const float4*)(eN + c0 + c0t + q * 64);
      en[4*q+0]=v.x; en[4*q+1]=v.y; en[4*q+2]=v.z; en[4*q+3]=v.w;
    }
    #pragma unroll
    for (int i = 0; i < 8; ++i) {
      #pragma unroll
      for (int q = 0; q < 4; ++q) {
        #pragma unroll
        for (int j = 0; j < 4; ++j) {
          const int jj = q * 4 + j;
          const float val = fmaf(-2.f, acc[i][jj], en[jj]);  // ||e||^2 - 2 z.e
          // index-ascending iteration -> strict < keeps first min
          if (val < minval[i]) { minval[i] = val; minidx[i] = c0 + c0t + q * 64 + j; }
        }
      }
    }
  }

  // ---- cross-colgrp argmin: butterfly over each 16-lane group ----
  #pragma unroll
  for (int i = 0; i < 8; ++i) {
    float v = minval[i];
    int  ix = minidx[i];
    #pragma unroll
    for (int m = 1; m < 16; m <<= 1) {
      const float v2 = __shfl_xor(v, m, 64);
      const int   i2 = __shfl_xor(ix, m, 64);
      if (v2 < v || (v2 == v && i2 < ix)) { v = v2; ix = i2; }
    }
    minidx[i] = ix;   // all 16 lanes of the group now agree
  }

  __syncthreads();                       // all e_lds reads done -> overlay
  int* bidx = (int*)e_lds0;              // [128]
  if (colgrp == 0) {
    #pragma unroll
    for (int i = 0; i < 8; ++i) {
      const int bi = minidx[i];
      bidx[r0 + i] = bi;
      out[O_IDX + n0 + r0 + i] = (float)bi;
      atomicAdd(ws + W_CNT + bi, 1.0f);
    }
  }
  __syncthreads();

  // ---- epilogue A: z_q = z + (e - z), coalesced over rows ----
  {
    const int row   = tid & 127;
    const int dhalf = tid >> 7;
    const int code  = bidx[row];
    const float* __restrict__ erow = ws + W_EMBT + (size_t)code * 64;
    const size_t obase = O_ZQ + (size_t)b * 262144 + (size_t)(hw0 + row);
    #pragma unroll
    for (int t = 0; t < 32; ++t) {
      const int d = dhalf * 32 + t;
      const float z = z_lds[d * 128 + row];
      const float e = erow[d];
      out[obase + (size_t)d * 4096] = z + (e - z);
    }
  }

  // ---- epilogue B: segment-sum, one coalesced atomic instruction per row ----
  {
    #pragma unroll 4
    for (int rr = 0; rr < 32; ++rr) {
      const int row  = wv * 32 + rr;
      const int code = bidx[row];
      atomicAdd(ws + W_UPD + (size_t)code * 64 + lane, z_lds[lane * 128 + row]);
    }
  }
}

// ---------------------------------------------------------------------------
// K3: EMA updates + normalization. Each block redundantly reduces n.
__global__ __launch_bounds__(256) void vq_final(const float* __restrict__ emb_ema,
                                                const float* __restrict__ counts_ema,
                                                const float* __restrict__ ws,
                                                float* __restrict__ out) {
  __shared__ float red[256];
  const int tid = threadIdx.x;
  const float* cnt = ws + W_CNT;

  float psum = 0.f;
  for (int t = tid; t < KCODES; t += 256) {
    const float ce  = counts_ema[t];
    const float cen = ce + 0.01f * (cnt[t] - ce);
    psum += cen;
    if (blockIdx.x == 0) out[O_CEN + t] = cen;
  }
  red[tid] = psum;
  __syncthreads();
  #pragma unroll
  for (int s = 128; s > 0; s >>= 1) {
    if (tid < s) red[tid] += red[tid + s];
    __syncthreads();
  }
  const float nsum = red[0];

  const int i = blockIdx.x * 256 + tid;   // 0..65535 over [D][K]
  const int d = i >> 10;
  const int k = i & 1023;

  const float ce  = counts_ema[k];
  const float cen = ce + 0.01f * (cnt[k] - ce);
  const float norm = (cen + 1e-5f) / (nsum + (float)KCODES * 1e-5f) * nsum;

  const float ema     = emb_ema[i];
  const float ema_new = ema + 0.01f * (ws[W_UPD + (size_t)k * 64 + d] - ema);
  out[O_EMA + i] = ema_new;
  out[O_EMB + i] = ema_new / norm;
}

// ---------------------------------------------------------------------------
extern "C" void kernel_launch(void* const* d_in, const int* in_sizes, int n_in,
                              void* d_out, int out_size, void* d_ws, size_t ws_size,
                              hipStream_t stream) {
  const float* z_e        = (const float*)d_in[0];
  const float* emb        = (const float*)d_in[1];
  const float* emb_ema    = (const float*)d_in[2];
  const float* counts_ema = (const float*)d_in[3];
  float* out = (float*)d_out;
  float* ws  = (float*)d_ws;

  vq_prep<<<16, 256, 0, stream>>>(emb, ws);
  vq_main<<<512, 256, 0, stream>>>(z_e, emb, ws, out);
  vq_final<<<256, 256, 0, stream>>>(emb_ema, counts_ema, ws, out);
}